// Round 2
// baseline (466.206 us; speedup 1.0000x reference)
//
#include <hip/hip_runtime.h>

// MHA forward: B=2, S=2048, HID=1024, NH=16, HD=64.
// R2: attn -> 8-wave blocks, barrier-free kv loop; GEMMs -> global_load_lds
//     (m97 structure), QKV fused into one grid.z=3 launch for 3 blocks/CU.

typedef unsigned short u16;
typedef unsigned int u32;
typedef __bf16 bf16x8 __attribute__((ext_vector_type(8)));
typedef float f32x4 __attribute__((ext_vector_type(4)));
typedef u16 u16x4 __attribute__((ext_vector_type(4)));

__device__ __forceinline__ u16 f2bf(float f) {
  union { float f; unsigned u; } x; x.f = f;
  unsigned r = (x.u + 0x7fffu + ((x.u >> 16) & 1u)) >> 16;  // RNE
  return (u16)r;
}

// async global->LDS, 16 B per lane. LDS dest must be wave-uniform base + lane*16.
__device__ __forceinline__ void gll16(const void* g, void* l) {
  __builtin_amdgcn_global_load_lds(
      (const __attribute__((address_space(1))) u32*)g,
      (__attribute__((address_space(3))) u32*)l, 16, 0, 0);
}

// ---------------- prep kernels ----------------

__global__ __launch_bounds__(256) void cast_kernel(const float* __restrict__ in,
                                                   u16* __restrict__ out, int n4) {
  int i = blockIdx.x * blockDim.x + threadIdx.x;
  if (i >= n4) return;
  float4 v = ((const float4*)in)[i];
  u16x4 o;
  o.x = f2bf(v.x); o.y = f2bf(v.y); o.z = f2bf(v.z); o.w = f2bf(v.w);
  ((u16x4*)out)[i] = o;
}

// WT[n][k] = bf16(W[k][n]); N fixed 1024
__global__ void transpose_cast(const float* __restrict__ W, u16* __restrict__ WT) {
  __shared__ float t[32][33];
  int bx = blockIdx.x * 32, by = blockIdx.y * 32;
  int tx = threadIdx.x, ty = threadIdx.y;  // block (32,8)
#pragma unroll
  for (int i = ty; i < 32; i += 8) t[i][tx] = W[(by + i) * 1024 + bx + tx];
  __syncthreads();
#pragma unroll
  for (int i = ty; i < 32; i += 8) WT[(bx + i) * 1024 + by + tx] = f2bf(t[tx][i]);
}

// ---------------- GEMM ----------------
// C = A(bf16,[M=4096,K=1024]) * B + bias, BT = B^T (bf16,[N=1024,K]).
// mode 0: fp32 row-major -> Cf
// mode 1: bf16 -> Cb[((b*16+h)*2048+s)*64+d]
// mode 2: bf16 -> Cb[((b*16+h)*64+d)*2048+s]  (V^T)
struct GemmJob {
  const u16* A; const u16* BT; const float* bias;
  float* Cf; u16* Cb; int mode;
};

__global__ __launch_bounds__(256) void gemm_multi(GemmJob j0, GemmJob j1, GemmJob j2) {
  GemmJob j = (blockIdx.z == 0) ? j0 : (blockIdx.z == 1) ? j1 : j2;
  const int K = 1024, N = 1024;
  __shared__ __align__(16) u16 As[128 * 64];  // unpadded: required by global_load_lds
  __shared__ __align__(16) u16 Bs[128 * 64];
  int tid = threadIdx.x;
  int bm = blockIdx.y * 128, bn = blockIdx.x * 128;
  int w = tid >> 6, lane = tid & 63, quad = lane >> 4, l16 = lane & 15;
  int wr = (w >> 1) * 64, wc = (w & 1) * 64;
  f32x4 acc[4][4] = {};

  for (int k0 = 0; k0 < K; k0 += 64) {
    __syncthreads();
#pragma unroll
    for (int i = 0; i < 4; ++i) {
      int s = tid + i * 256;            // 16B chunk index, 0..1023
      int r = s >> 3, c = (s & 7) * 8;
      gll16(&j.A[(size_t)(bm + r) * K + k0 + c], &As[s * 8]);
      gll16(&j.BT[(size_t)(bn + r) * K + k0 + c], &Bs[s * 8]);
    }
    __syncthreads();  // compiler drains vmcnt(0) here
#pragma unroll
    for (int ks = 0; ks < 2; ++ks) {
      int kc = ks * 32 + quad * 8;
      bf16x8 af[4], bfr[4];
#pragma unroll
      for (int mt = 0; mt < 4; ++mt) af[mt] = *(const bf16x8*)&As[(wr + mt * 16 + l16) * 64 + kc];
#pragma unroll
      for (int nt = 0; nt < 4; ++nt) bfr[nt] = *(const bf16x8*)&Bs[(wc + nt * 16 + l16) * 64 + kc];
#pragma unroll
      for (int mt = 0; mt < 4; ++mt)
#pragma unroll
        for (int nt = 0; nt < 4; ++nt)
          acc[mt][nt] = __builtin_amdgcn_mfma_f32_16x16x32_bf16(af[mt], bfr[nt], acc[mt][nt], 0, 0, 0);
    }
  }

#pragma unroll
  for (int mt = 0; mt < 4; ++mt)
#pragma unroll
    for (int nt = 0; nt < 4; ++nt)
#pragma unroll
      for (int r = 0; r < 4; ++r) {
        int row = bm + wr + mt * 16 + quad * 4 + r;
        int col = bn + wc + nt * 16 + l16;
        float v = acc[mt][nt][r] + j.bias[col];
        if (j.mode == 0) {
          j.Cf[(size_t)row * N + col] = v;
        } else {
          int b = row >> 11, s = row & 2047, h = col >> 6, d = col & 63;
          u16 bv = f2bf(v);
          if (j.mode == 1)
            j.Cb[(((size_t)(b * 16 + h) * 2048 + s) << 6) + d] = bv;
          else
            j.Cb[((size_t)(b * 16 + h) * 64 + d) * 2048 + s] = bv;
        }
      }
}

// ---------------- flash attention ----------------
// grid (16 qtiles, 16 heads, 2 batch), block 512 = 8 waves x 16 query rows.
// Barrier-free: each wave's 16 rows of Ps are private to it.
__global__ __launch_bounds__(512) void attn_kernel(
    const u16* __restrict__ Q,   // [B*NH, S, 64]
    const u16* __restrict__ Kk,  // [B*NH, S, 64]
    const u16* __restrict__ VT,  // [B*NH, 64, S]
    u16* __restrict__ ctx)       // [B*S, 1024]
{
  __shared__ __align__(16) u16 Ps[128][136];
  int qt = blockIdx.x, h = blockIdx.y, b = blockIdx.z;
  int bh = b * 16 + h;
  const u16* Qb = Q + ((size_t)bh * 2048 + qt * 128) * 64;
  const u16* Kb = Kk + (size_t)bh * 2048 * 64;
  const u16* Vb = VT + (size_t)bh * 64 * 2048;
  int tid = threadIdx.x, w = tid >> 6, lane = tid & 63, quad = lane >> 4, l16 = lane & 15;
  int rowbase = w * 16;

  bf16x8 qf[2];
#pragma unroll
  for (int ks = 0; ks < 2; ++ks)
    qf[ks] = *(const bf16x8*)&Qb[(rowbase + l16) * 64 + ks * 32 + quad * 8];

  f32x4 Oacc[4] = {};
  float m_old[4], l_old[4];
#pragma unroll
  for (int r = 0; r < 4; ++r) { m_old[r] = -INFINITY; l_old[r] = 0.f; }

  const float sc = 0.125f * 1.44269504f;  // 1/sqrt(64) * log2(e)

  for (int kv = 0; kv < 16; ++kv) {
    int kbase = kv * 128;
    f32x4 Sacc[8] = {};
#pragma unroll
    for (int nt = 0; nt < 8; ++nt) {
      int krow = kbase + nt * 16 + l16;
#pragma unroll
      for (int ks = 0; ks < 2; ++ks) {
        bf16x8 kfr = *(const bf16x8*)&Kb[(size_t)krow * 64 + ks * 32 + quad * 8];
        Sacc[nt] = __builtin_amdgcn_mfma_f32_16x16x32_bf16(qf[ks], kfr, Sacc[nt], 0, 0, 0);
      }
    }
#pragma unroll
    for (int nt = 0; nt < 8; ++nt) Sacc[nt] *= sc;

#pragma unroll
    for (int r = 0; r < 4; ++r) {
      float mx = Sacc[0][r];
#pragma unroll
      for (int nt = 1; nt < 8; ++nt) mx = fmaxf(mx, Sacc[nt][r]);
#pragma unroll
      for (int s = 1; s < 16; s <<= 1) mx = fmaxf(mx, __shfl_xor(mx, s, 64));
      float mn = fmaxf(m_old[r], mx);
      float alpha = exp2f(m_old[r] - mn);
      m_old[r] = mn;
      float rs = 0.f;
#pragma unroll
      for (int nt = 0; nt < 8; ++nt) {
        float p = exp2f(Sacc[nt][r] - mn);
        Sacc[nt][r] = p;
        rs += p;
      }
#pragma unroll
      for (int s = 1; s < 16; s <<= 1) rs += __shfl_xor(rs, s, 64);
      l_old[r] = alpha * l_old[r] + rs;
#pragma unroll
      for (int dt = 0; dt < 4; ++dt) Oacc[dt][r] *= alpha;
    }

    // P: C/D layout -> LDS -> A layout. Rows [rowbase, rowbase+16) are
    // wave-private: no __syncthreads needed (compiler orders same-wave DS ops).
#pragma unroll
    for (int nt = 0; nt < 8; ++nt)
#pragma unroll
      for (int r = 0; r < 4; ++r)
        Ps[rowbase + quad * 4 + r][nt * 16 + l16] = f2bf(Sacc[nt][r]);

#pragma unroll
    for (int ks2 = 0; ks2 < 4; ++ks2) {
      int kc = ks2 * 32 + quad * 8;
      bf16x8 pf = *(const bf16x8*)&Ps[rowbase + l16][kc];
#pragma unroll
      for (int dt = 0; dt < 4; ++dt) {
        bf16x8 vf = *(const bf16x8*)&Vb[(size_t)(dt * 16 + l16) * 2048 + kbase + kc];
        Oacc[dt] = __builtin_amdgcn_mfma_f32_16x16x32_bf16(pf, vf, Oacc[dt], 0, 0, 0);
      }
    }
  }

#pragma unroll
  for (int dt = 0; dt < 4; ++dt)
#pragma unroll
    for (int r = 0; r < 4; ++r) {
      int srow = qt * 128 + rowbase + quad * 4 + r;
      int d = dt * 16 + l16;
      float v = Oacc[dt][r] / l_old[r];
      ctx[(size_t)(b * 2048 + srow) * 1024 + h * 64 + d] = f2bf(v);
    }
}

// ---------------- launch ----------------

extern "C" void kernel_launch(void* const* d_in, const int* in_sizes, int n_in,
                              void* d_out, int out_size, void* d_ws, size_t ws_size,
                              hipStream_t stream) {
  const float* query = (const float*)d_in[0];
  const float* key_  = (const float*)d_in[1];
  const float* value = (const float*)d_in[2];
  const float* Wq = (const float*)d_in[3];
  const float* bq = (const float*)d_in[4];
  const float* Wk = (const float*)d_in[5];
  const float* bk = (const float*)d_in[6];
  const float* Wv = (const float*)d_in[7];
  const float* bv = (const float*)d_in[8];
  const float* Wo = (const float*)d_in[9];
  const float* bo = (const float*)d_in[10];
  float* out = (float*)d_out;

  char* ws = (char*)d_ws;
  const size_t MB = 1024 * 1024;
  u16* Aq  = (u16*)(ws + 0 * MB);
  u16* Ak  = (u16*)(ws + 8 * MB);
  u16* Av  = (u16*)(ws + 16 * MB);
  u16* WqT = (u16*)(ws + 24 * MB);
  u16* WkT = (u16*)(ws + 26 * MB);
  u16* WvT = (u16*)(ws + 28 * MB);
  u16* WoT = (u16*)(ws + 30 * MB);
  u16* Qp  = (u16*)(ws + 32 * MB);
  u16* Kp  = (u16*)(ws + 40 * MB);
  u16* VTp = (u16*)(ws + 48 * MB);
  u16* Ctx = (u16*)(ws + 56 * MB);

  cast_kernel<<<4096, 256, 0, stream>>>(query, Aq, 1048576);
  cast_kernel<<<4096, 256, 0, stream>>>(key_, Ak, 1048576);
  cast_kernel<<<4096, 256, 0, stream>>>(value, Av, 1048576);

  dim3 tb(32, 8), tg(32, 32);
  transpose_cast<<<tg, tb, 0, stream>>>(Wq, WqT);
  transpose_cast<<<tg, tb, 0, stream>>>(Wk, WkT);
  transpose_cast<<<tg, tb, 0, stream>>>(Wv, WvT);
  transpose_cast<<<tg, tb, 0, stream>>>(Wo, WoT);

  GemmJob jq{Aq, WqT, bq, nullptr, Qp, 1};
  GemmJob jk{Ak, WkT, bk, nullptr, Kp, 1};
  GemmJob jv{Av, WvT, bv, nullptr, VTp, 2};
  gemm_multi<<<dim3(8, 32, 3), 256, 0, stream>>>(jq, jk, jv);

  attn_kernel<<<dim3(16, 16, 2), 512, 0, stream>>>(Qp, Kp, VTp, Ctx);

  GemmJob jo{Ctx, WoT, bo, out, nullptr, 0};
  gemm_multi<<<dim3(8, 32, 1), 256, 0, stream>>>(jo, jo, jo);
}

// Round 3
// 463.973 us; speedup vs baseline: 1.0048x; 1.0048x over previous
//
#include <hip/hip_runtime.h>

// MHA forward: B=2, S=2048, HID=1024, NH=16, HD=64.
// R3: attention restructured: S^T formulation + fixed-max softmax (M=24, base-2).
//     No shuffle reductions, P^T via 8x ds_write_b64 + 4x ds_read_b128 per kv
//     (was 68 DS ops -> 12). Barrier-free. GEMMs unchanged from R2.

typedef unsigned short u16;
typedef unsigned int u32;
typedef __bf16 bf16x8 __attribute__((ext_vector_type(8)));
typedef float f32x4 __attribute__((ext_vector_type(4)));
typedef u16 u16x4 __attribute__((ext_vector_type(4)));

__device__ __forceinline__ u16 f2bf(float f) {
  union { float f; unsigned u; } x; x.f = f;
  unsigned r = (x.u + 0x7fffu + ((x.u >> 16) & 1u)) >> 16;  // RNE
  return (u16)r;
}

// async global->LDS, 16 B per lane. LDS dest must be wave-uniform base + lane*16.
__device__ __forceinline__ void gll16(const void* g, void* l) {
  __builtin_amdgcn_global_load_lds(
      (const __attribute__((address_space(1))) u32*)g,
      (__attribute__((address_space(3))) u32*)l, 16, 0, 0);
}

// ---------------- prep kernels ----------------

__global__ __launch_bounds__(256) void cast_kernel(const float* __restrict__ in,
                                                   u16* __restrict__ out, int n4) {
  int i = blockIdx.x * blockDim.x + threadIdx.x;
  if (i >= n4) return;
  float4 v = ((const float4*)in)[i];
  u16x4 o;
  o.x = f2bf(v.x); o.y = f2bf(v.y); o.z = f2bf(v.z); o.w = f2bf(v.w);
  ((u16x4*)out)[i] = o;
}

// WT[n][k] = bf16(W[k][n]); N fixed 1024
__global__ void transpose_cast(const float* __restrict__ W, u16* __restrict__ WT) {
  __shared__ float t[32][33];
  int bx = blockIdx.x * 32, by = blockIdx.y * 32;
  int tx = threadIdx.x, ty = threadIdx.y;  // block (32,8)
#pragma unroll
  for (int i = ty; i < 32; i += 8) t[i][tx] = W[(by + i) * 1024 + bx + tx];
  __syncthreads();
#pragma unroll
  for (int i = ty; i < 32; i += 8) WT[(bx + i) * 1024 + by + tx] = f2bf(t[tx][i]);
}

// ---------------- GEMM (unchanged from R2) ----------------
struct GemmJob {
  const u16* A; const u16* BT; const float* bias;
  float* Cf; u16* Cb; int mode;
};

__global__ __launch_bounds__(256) void gemm_multi(GemmJob j0, GemmJob j1, GemmJob j2) {
  GemmJob j = (blockIdx.z == 0) ? j0 : (blockIdx.z == 1) ? j1 : j2;
  const int K = 1024, N = 1024;
  __shared__ __align__(16) u16 As[128 * 64];
  __shared__ __align__(16) u16 Bs[128 * 64];
  int tid = threadIdx.x;
  int bm = blockIdx.y * 128, bn = blockIdx.x * 128;
  int w = tid >> 6, lane = tid & 63, quad = lane >> 4, l16 = lane & 15;
  int wr = (w >> 1) * 64, wc = (w & 1) * 64;
  f32x4 acc[4][4] = {};

  for (int k0 = 0; k0 < K; k0 += 64) {
    __syncthreads();
#pragma unroll
    for (int i = 0; i < 4; ++i) {
      int s = tid + i * 256;
      int r = s >> 3, c = (s & 7) * 8;
      gll16(&j.A[(size_t)(bm + r) * K + k0 + c], &As[s * 8]);
      gll16(&j.BT[(size_t)(bn + r) * K + k0 + c], &Bs[s * 8]);
    }
    __syncthreads();
#pragma unroll
    for (int ks = 0; ks < 2; ++ks) {
      int kc = ks * 32 + quad * 8;
      bf16x8 af[4], bfr[4];
#pragma unroll
      for (int mt = 0; mt < 4; ++mt) af[mt] = *(const bf16x8*)&As[(wr + mt * 16 + l16) * 64 + kc];
#pragma unroll
      for (int nt = 0; nt < 4; ++nt) bfr[nt] = *(const bf16x8*)&Bs[(wc + nt * 16 + l16) * 64 + kc];
#pragma unroll
      for (int mt = 0; mt < 4; ++mt)
#pragma unroll
        for (int nt = 0; nt < 4; ++nt)
          acc[mt][nt] = __builtin_amdgcn_mfma_f32_16x16x32_bf16(af[mt], bfr[nt], acc[mt][nt], 0, 0, 0);
    }
  }

#pragma unroll
  for (int mt = 0; mt < 4; ++mt)
#pragma unroll
    for (int nt = 0; nt < 4; ++nt)
#pragma unroll
      for (int r = 0; r < 4; ++r) {
        int row = bm + wr + mt * 16 + quad * 4 + r;
        int col = bn + wc + nt * 16 + l16;
        float v = acc[mt][nt][r] + j.bias[col];
        if (j.mode == 0) {
          j.Cf[(size_t)row * N + col] = v;
        } else {
          int b = row >> 11, s = row & 2047, h = col >> 6, d = col & 63;
          u16 bv = f2bf(v);
          if (j.mode == 1)
            j.Cb[(((size_t)(b * 16 + h) * 2048 + s) << 6) + d] = bv;
          else
            j.Cb[((size_t)(b * 16 + h) * 64 + d) * 2048 + s] = bv;
        }
      }
}

// ---------------- flash attention (S^T, fixed-max) ----------------
// grid (16 qtiles, 16 heads, 2 batch), block 512 = 8 waves x 16 query rows.
// S^T = mfma(K-frag, Q-frag): lane holds fixed q-col (l16), 4 consecutive k-rows.
// P^T -> LDS via packed b64 writes; PV: O^T = mfma(V-frag, P^T-frag).
// Fixed max M=24 (base-2): removes all reductions; l accumulated per-lane.
__global__ __launch_bounds__(512) void attn_kernel(
    const u16* __restrict__ Q,   // [B*NH, S, 64]
    const u16* __restrict__ Kk,  // [B*NH, S, 64]
    const u16* __restrict__ VT,  // [B*NH, 64, S]
    u16* __restrict__ ctx)       // [B*S, 1024]
{
  __shared__ __align__(16) u16 PT[8][16][136];  // per-wave [q=16][k=128+pad]
  int qt = blockIdx.x, h = blockIdx.y, b = blockIdx.z;
  int bh = b * 16 + h;
  const u16* Qb = Q + ((size_t)bh * 2048 + qt * 128) * 64;
  const u16* Kb = Kk + (size_t)bh * 2048 * 64;
  const u16* Vb = VT + (size_t)bh * 64 * 2048;
  int tid = threadIdx.x, w = tid >> 6, lane = tid & 63, quad = lane >> 4, l16 = lane & 15;
  int rowbase = w * 16;

  // Q as B-operand: B[k=d=quad*8+j][n=q=l16]
  bf16x8 qf[2];
#pragma unroll
  for (int ks = 0; ks < 2; ++ks)
    qf[ks] = *(const bf16x8*)&Qb[(rowbase + l16) * 64 + ks * 32 + quad * 8];

  f32x4 Oacc[4] = {};   // O^T: rows d=dt*16+quad*4+r, col q=l16
  float lacc = 0.f;     // partial row-sum of P for col q=l16 over this lane's k-rows

  const float sc = 0.125f * 1.44269504f;  // 1/sqrt(64) * log2(e)

  for (int kv = 0; kv < 16; ++kv) {
    int kbase = kv * 128;
    // S^T tiles: nt over 8 k-row groups of 16
    f32x4 Sacc[8] = {};
#pragma unroll
    for (int nt = 0; nt < 8; ++nt) {
      int krow = kbase + nt * 16 + l16;  // A-frag: m=l16
#pragma unroll
      for (int ks = 0; ks < 2; ++ks) {
        bf16x8 kfr = *(const bf16x8*)&Kb[(size_t)krow * 64 + ks * 32 + quad * 8];
        Sacc[nt] = __builtin_amdgcn_mfma_f32_16x16x32_bf16(kfr, qf[ks], Sacc[nt], 0, 0, 0);
      }
    }

    // p = exp2(sc*S - 24); pack 4 consecutive k-rows -> one b64 LDS write
#pragma unroll
    for (int nt = 0; nt < 8; ++nt) {
      u16x4 pk;
#pragma unroll
      for (int r = 0; r < 4; ++r) {
        float p = exp2f(fmaf(Sacc[nt][r], sc, -24.0f));
        lacc += p;
        pk[r] = f2bf(p);
      }
      *(u16x4*)&PT[w][l16][nt * 16 + quad * 4] = pk;
    }

    // PV: O^T += V-frag * P^T-frag  (same-wave DS write->read; HW orders in-wave)
#pragma unroll
    for (int ks2 = 0; ks2 < 4; ++ks2) {
      bf16x8 pfB = *(const bf16x8*)&PT[w][l16][ks2 * 32 + quad * 8];
#pragma unroll
      for (int dt = 0; dt < 4; ++dt) {
        bf16x8 vf = *(const bf16x8*)&Vb[(size_t)(dt * 16 + l16) * 2048 + kbase + ks2 * 32 + quad * 8];
        Oacc[dt] = __builtin_amdgcn_mfma_f32_16x16x32_bf16(vf, pfB, Oacc[dt], 0, 0, 0);
      }
    }
  }

  // l for q=l16: sum this lane's partial over the 4 quad groups
  float l = lacc;
  l += __shfl_xor(l, 16, 64);
  l += __shfl_xor(l, 32, 64);
  float linv = 1.0f / l;

  int s = qt * 128 + rowbase + l16;
#pragma unroll
  for (int dt = 0; dt < 4; ++dt) {
    u16x4 o;
#pragma unroll
    for (int r = 0; r < 4; ++r) o[r] = f2bf(Oacc[dt][r] * linv);
    *(u16x4*)&ctx[(size_t)(b * 2048 + s) * 1024 + h * 64 + dt * 16 + quad * 4] = o;
  }
}

// ---------------- launch ----------------

extern "C" void kernel_launch(void* const* d_in, const int* in_sizes, int n_in,
                              void* d_out, int out_size, void* d_ws, size_t ws_size,
                              hipStream_t stream) {
  const float* query = (const float*)d_in[0];
  const float* key_  = (const float*)d_in[1];
  const float* value = (const float*)d_in[2];
  const float* Wq = (const float*)d_in[3];
  const float* bq = (const float*)d_in[4];
  const float* Wk = (const float*)d_in[5];
  const float* bk = (const float*)d_in[6];
  const float* Wv = (const float*)d_in[7];
  const float* bv = (const float*)d_in[8];
  const float* Wo = (const float*)d_in[9];
  const float* bo = (const float*)d_in[10];
  float* out = (float*)d_out;

  char* ws = (char*)d_ws;
  const size_t MB = 1024 * 1024;
  u16* Aq  = (u16*)(ws + 0 * MB);
  u16* Ak  = (u16*)(ws + 8 * MB);
  u16* Av  = (u16*)(ws + 16 * MB);
  u16* WqT = (u16*)(ws + 24 * MB);
  u16* WkT = (u16*)(ws + 26 * MB);
  u16* WvT = (u16*)(ws + 28 * MB);
  u16* WoT = (u16*)(ws + 30 * MB);
  u16* Qp  = (u16*)(ws + 32 * MB);
  u16* Kp  = (u16*)(ws + 40 * MB);
  u16* VTp = (u16*)(ws + 48 * MB);
  u16* Ctx = (u16*)(ws + 56 * MB);

  cast_kernel<<<4096, 256, 0, stream>>>(query, Aq, 1048576);
  cast_kernel<<<4096, 256, 0, stream>>>(key_, Ak, 1048576);
  cast_kernel<<<4096, 256, 0, stream>>>(value, Av, 1048576);

  dim3 tb(32, 8), tg(32, 32);
  transpose_cast<<<tg, tb, 0, stream>>>(Wq, WqT);
  transpose_cast<<<tg, tb, 0, stream>>>(Wk, WkT);
  transpose_cast<<<tg, tb, 0, stream>>>(Wv, WvT);
  transpose_cast<<<tg, tb, 0, stream>>>(Wo, WoT);

  GemmJob jq{Aq, WqT, bq, nullptr, Qp, 1};
  GemmJob jk{Ak, WkT, bk, nullptr, Kp, 1};
  GemmJob jv{Av, WvT, bv, nullptr, VTp, 2};
  gemm_multi<<<dim3(8, 32, 3), 256, 0, stream>>>(jq, jk, jv);

  attn_kernel<<<dim3(16, 16, 2), 512, 0, stream>>>(Qp, Kp, VTp, Ctx);

  GemmJob jo{Ctx, WoT, bo, out, nullptr, 0};
  gemm_multi<<<dim3(8, 32, 1), 256, 0, stream>>>(jo, jo, jo);
}

// Round 4
// 284.511 us; speedup vs baseline: 1.6386x; 1.6308x over previous
//
#include <hip/hip_runtime.h>

// MHA forward: B=2, S=2048, HID=1024, NH=16, HD=64.
// R4: attn: K/V staged to LDS via global_load_lds (shared across 8 waves, was
//     8x redundant global streams); XCD-aware head grouping (blk&7 -> XCD, 4
//     heads/XCD = 2MB L2 set, was 16MB thrash); XOR-swizzled LDS (conflict-free
//     column reads, swizzle on global fetch index since gll16 pins LDS dest).
//     GEMM: same XOR swizzle on A/B tiles. Prep launches fused.

typedef unsigned short u16;
typedef unsigned int u32;
typedef __bf16 bf16x8 __attribute__((ext_vector_type(8)));
typedef float f32x4 __attribute__((ext_vector_type(4)));
typedef u16 u16x4 __attribute__((ext_vector_type(4)));

__device__ __forceinline__ u16 f2bf(float f) {
  union { float f; unsigned u; } x; x.f = f;
  unsigned r = (x.u + 0x7fffu + ((x.u >> 16) & 1u)) >> 16;  // RNE
  return (u16)r;
}

// async global->LDS, 16 B per lane. LDS dest is wave-uniform base + lane*16.
__device__ __forceinline__ void gll16(const void* g, void* l) {
  __builtin_amdgcn_global_load_lds(
      (const __attribute__((address_space(1))) u32*)g,
      (__attribute__((address_space(3))) u32*)l, 16, 0, 0);
}

// ---------------- prep kernels (fused) ----------------

__global__ __launch_bounds__(256) void cast3_kernel(
    const float* __restrict__ a0, const float* __restrict__ a1,
    const float* __restrict__ a2,
    u16* __restrict__ o0, u16* __restrict__ o1, u16* __restrict__ o2) {
  const float* in = (blockIdx.y == 0) ? a0 : (blockIdx.y == 1) ? a1 : a2;
  u16* out = (blockIdx.y == 0) ? o0 : (blockIdx.y == 1) ? o1 : o2;
  int i = blockIdx.x * 256 + threadIdx.x;  // 1<<20 float4 groups
  float4 v = ((const float4*)in)[i];
  u16x4 o;
  o.x = f2bf(v.x); o.y = f2bf(v.y); o.z = f2bf(v.z); o.w = f2bf(v.w);
  ((u16x4*)out)[i] = o;
}

// WT[n][k] = bf16(W[k][n]); 1024x1024, 4 weights in one launch (blockIdx.z)
__global__ void transpose4_kernel(
    const float* __restrict__ W0, const float* __restrict__ W1,
    const float* __restrict__ W2, const float* __restrict__ W3,
    u16* __restrict__ T0, u16* __restrict__ T1,
    u16* __restrict__ T2, u16* __restrict__ T3) {
  const float* W = (blockIdx.z == 0) ? W0 : (blockIdx.z == 1) ? W1
                  : (blockIdx.z == 2) ? W2 : W3;
  u16* WT = (blockIdx.z == 0) ? T0 : (blockIdx.z == 1) ? T1
           : (blockIdx.z == 2) ? T2 : T3;
  __shared__ float t[32][33];
  int bx = blockIdx.x * 32, by = blockIdx.y * 32;
  int tx = threadIdx.x, ty = threadIdx.y;  // block (32,8)
#pragma unroll
  for (int i = ty; i < 32; i += 8) t[i][tx] = W[(by + i) * 1024 + bx + tx];
  __syncthreads();
#pragma unroll
  for (int i = ty; i < 32; i += 8) WT[(bx + i) * 1024 + by + tx] = f2bf(t[tx][i]);
}

// ---------------- GEMM ----------------
// C = A(bf16,[M=4096,K=1024]) * B + bias, BT = B^T (bf16,[N=1024,K]).
// LDS tiles 128x64, XOR-swizzled: LDS slot (r, j') holds global 16B-chunk
// (r, j' ^ (r&7)). Column reads become <=2-way bank aliased (free).
struct GemmJob {
  const u16* A; const u16* BT; const float* bias;
  float* Cf; u16* Cb; int mode;
};

__global__ __launch_bounds__(256) void gemm_multi(GemmJob j0, GemmJob j1, GemmJob j2) {
  GemmJob j = (blockIdx.z == 0) ? j0 : (blockIdx.z == 1) ? j1 : j2;
  const int K = 1024, N = 1024;
  __shared__ __align__(16) u16 As[128 * 64];
  __shared__ __align__(16) u16 Bs[128 * 64];
  int tid = threadIdx.x;
  int bm = blockIdx.y * 128, bn = blockIdx.x * 128;
  int w = tid >> 6, lane = tid & 63, quad = lane >> 4, l16 = lane & 15;
  int wr = (w >> 1) * 64, wc = (w & 1) * 64;
  int l8 = l16 & 7;
  f32x4 acc[4][4] = {};

  for (int k0 = 0; k0 < K; k0 += 64) {
    __syncthreads();
#pragma unroll
    for (int i = 0; i < 4; ++i) {
      int c = tid + i * 256;                 // LDS chunk slot 0..1023
      int r = c >> 3, jp = c & 7;
      int jg = jp ^ (r & 7);                 // global chunk (XOR swizzle)
      gll16(&j.A[(size_t)(bm + r) * K + k0 + jg * 8], &As[c * 8]);
      gll16(&j.BT[(size_t)(bn + r) * K + k0 + jg * 8], &Bs[c * 8]);
    }
    __syncthreads();
#pragma unroll
    for (int ks = 0; ks < 2; ++ks) {
      bf16x8 af[4], bfr[4];
#pragma unroll
      for (int mt = 0; mt < 4; ++mt) {
        int row = wr + mt * 16 + l16;
        af[mt] = *(const bf16x8*)&As[row * 64 + (((ks * 4 + quad) ^ l8)) * 8];
      }
#pragma unroll
      for (int nt = 0; nt < 4; ++nt) {
        int row = wc + nt * 16 + l16;
        bfr[nt] = *(const bf16x8*)&Bs[row * 64 + (((ks * 4 + quad) ^ l8)) * 8];
      }
#pragma unroll
      for (int mt = 0; mt < 4; ++mt)
#pragma unroll
        for (int nt = 0; nt < 4; ++nt)
          acc[mt][nt] = __builtin_amdgcn_mfma_f32_16x16x32_bf16(af[mt], bfr[nt], acc[mt][nt], 0, 0, 0);
    }
  }

#pragma unroll
  for (int mt = 0; mt < 4; ++mt)
#pragma unroll
    for (int nt = 0; nt < 4; ++nt)
#pragma unroll
      for (int r = 0; r < 4; ++r) {
        int row = bm + wr + mt * 16 + quad * 4 + r;
        int col = bn + wc + nt * 16 + l16;
        float v = acc[mt][nt][r] + j.bias[col];
        if (j.mode == 0) {
          j.Cf[(size_t)row * N + col] = v;
        } else {
          int b = row >> 11, s = row & 2047, h = col >> 6, d = col & 63;
          u16 bv = f2bf(v);
          if (j.mode == 1)
            j.Cb[(((size_t)(b * 16 + h) * 2048 + s) << 6) + d] = bv;
          else
            j.Cb[((size_t)(b * 16 + h) * 64 + d) * 2048 + s] = bv;
        }
      }
}

// ---------------- flash attention (R4) ----------------
// Flat grid 512, block 512 (8 waves x 16 q-rows).
// blk&7 -> XCD (round-robin heuristic); bh = (blk&7)*4 + (blk>>7) groups all
// 16 q-tiles of a head on one XCD.  K-tile [128k x 64d] and V-tile [64d x 128k]
// staged to LDS per kv-iter via gll16 (coalesced, shared by all waves).
// S^T formulation + fixed-max softmax (M=24, base-2), P^T wave-private in LDS.
__global__ __launch_bounds__(512) void attn_kernel(
    const u16* __restrict__ Q,   // [B*NH, S, 64]
    const u16* __restrict__ Kk,  // [B*NH, S, 64]
    const u16* __restrict__ VT,  // [B*NH, 64, S]
    u16* __restrict__ ctx)       // [B*S, 1024]
{
  __shared__ __align__(16) u16 Ks[128 * 64];      // 16 KB, swizzle j^(r&7) on 8-chunk rows
  __shared__ __align__(16) u16 Vs[64 * 128];      // 16 KB, swizzle j^(d&15) on 16-chunk rows
  __shared__ __align__(16) u16 PT[8 * 16 * 128];  // 32 KB, swizzle j^q on 16-chunk rows

  int blk = blockIdx.x;
  int qt = (blk >> 3) & 15;
  int bh = (blk & 7) * 4 + (blk >> 7);
  int b = bh >> 4, h = bh & 15;
  const u16* Qb = Q + ((size_t)bh * 2048 + qt * 128) * 64;
  const u16* Kb = Kk + (size_t)bh * 2048 * 64;
  const u16* Vb = VT + (size_t)bh * 64 * 2048;
  int tid = threadIdx.x, w = tid >> 6, lane = tid & 63, quad = lane >> 4, l16 = lane & 15;
  int rowbase = w * 16;
  u16* PTw = &PT[w * 16 * 128];

  // Q as B-operand: B[k=d][n=q=l16]
  bf16x8 qf[2];
#pragma unroll
  for (int ks = 0; ks < 2; ++ks)
    qf[ks] = *(const bf16x8*)&Qb[(rowbase + l16) * 64 + ks * 32 + quad * 8];

  f32x4 Oacc[4] = {};   // O^T rows d=dt*16+quad*4+r, col q=l16
  float lacc = 0.f;
  const float sc = 0.125f * 1.44269504f;  // 1/sqrt(64)*log2(e)

  for (int kv = 0; kv < 16; ++kv) {
    int kbase = kv * 128;
    __syncthreads();
    // stage K tile: 1024 chunks of 16B; rows r (k-dim), 8 chunks/row
#pragma unroll
    for (int i = 0; i < 2; ++i) {
      int c = tid + i * 512;
      int r = c >> 3, jp = c & 7, jg = jp ^ (r & 7);
      gll16(&Kb[(size_t)(kbase + r) * 64 + jg * 8], &Ks[c * 8]);
    }
    // stage V tile: rows d (0..63), 16 chunks/row
#pragma unroll
    for (int i = 0; i < 2; ++i) {
      int c = tid + i * 512;
      int d = c >> 4, jp = c & 15, jg = jp ^ (d & 15);
      gll16(&Vb[(size_t)d * 2048 + kbase + jg * 8], &Vs[c * 8]);
    }
    __syncthreads();

    // S^T = mfma(A=K-frag, B=Q-frag)
    f32x4 Sacc[8] = {};
#pragma unroll
    for (int nt = 0; nt < 8; ++nt) {
      int r = nt * 16 + l16;
#pragma unroll
      for (int ks = 0; ks < 2; ++ks) {
        bf16x8 kfr = *(const bf16x8*)&Ks[r * 64 + ((ks * 4 + quad) ^ (l16 & 7)) * 8];
        Sacc[nt] = __builtin_amdgcn_mfma_f32_16x16x32_bf16(kfr, qf[ks], Sacc[nt], 0, 0, 0);
      }
    }

    // p = exp2(sc*S - 24); pack 4 k-rows -> b64 write into swizzled PT
#pragma unroll
    for (int nt = 0; nt < 8; ++nt) {
      u16x4 pk;
#pragma unroll
      for (int r = 0; r < 4; ++r) {
        float p = exp2f(fmaf(Sacc[nt][r], sc, -24.0f));
        lacc += p;
        pk[r] = f2bf(p);
      }
      int j = nt * 2 + (quad >> 1);          // 16B chunk within q-row
      *(u16x4*)&PTw[l16 * 128 + ((j ^ l16) * 8) + (quad & 1) * 4] = pk;
    }

    // PV: O^T += mfma(A=V-frag, B=P^T-frag)   (same-wave DS write->read)
#pragma unroll
    for (int ks2 = 0; ks2 < 4; ++ks2) {
      bf16x8 pfB = *(const bf16x8*)&PTw[l16 * 128 + (((ks2 * 4 + quad) ^ l16)) * 8];
#pragma unroll
      for (int dt = 0; dt < 4; ++dt) {
        int d = dt * 16 + l16;
        bf16x8 vf = *(const bf16x8*)&Vs[d * 128 + (((ks2 * 4 + quad) ^ l16)) * 8];
        Oacc[dt] = __builtin_amdgcn_mfma_f32_16x16x32_bf16(vf, pfB, Oacc[dt], 0, 0, 0);
      }
    }
  }

  float l = lacc;
  l += __shfl_xor(l, 16, 64);
  l += __shfl_xor(l, 32, 64);
  float linv = 1.0f / l;

  int s = qt * 128 + rowbase + l16;
#pragma unroll
  for (int dt = 0; dt < 4; ++dt) {
    u16x4 o;
#pragma unroll
    for (int r = 0; r < 4; ++r) o[r] = f2bf(Oacc[dt][r] * linv);
    *(u16x4*)&ctx[(size_t)(b * 2048 + s) * 1024 + h * 64 + dt * 16 + quad * 4] = o;
  }
}

// ---------------- launch ----------------

extern "C" void kernel_launch(void* const* d_in, const int* in_sizes, int n_in,
                              void* d_out, int out_size, void* d_ws, size_t ws_size,
                              hipStream_t stream) {
  const float* query = (const float*)d_in[0];
  const float* key_  = (const float*)d_in[1];
  const float* value = (const float*)d_in[2];
  const float* Wq = (const float*)d_in[3];
  const float* bq = (const float*)d_in[4];
  const float* Wk = (const float*)d_in[5];
  const float* bk = (const float*)d_in[6];
  const float* Wv = (const float*)d_in[7];
  const float* bv = (const float*)d_in[8];
  const float* Wo = (const float*)d_in[9];
  const float* bo = (const float*)d_in[10];
  float* out = (float*)d_out;

  char* ws = (char*)d_ws;
  const size_t MB = 1024 * 1024;
  u16* Aq  = (u16*)(ws + 0 * MB);
  u16* Ak  = (u16*)(ws + 8 * MB);
  u16* Av  = (u16*)(ws + 16 * MB);
  u16* WqT = (u16*)(ws + 24 * MB);
  u16* WkT = (u16*)(ws + 26 * MB);
  u16* WvT = (u16*)(ws + 28 * MB);
  u16* WoT = (u16*)(ws + 30 * MB);
  u16* Qp  = (u16*)(ws + 32 * MB);
  u16* Kp  = (u16*)(ws + 40 * MB);
  u16* VTp = (u16*)(ws + 48 * MB);
  u16* Ctx = (u16*)(ws + 56 * MB);

  cast3_kernel<<<dim3(4096, 3), 256, 0, stream>>>(query, key_, value, Aq, Ak, Av);
  transpose4_kernel<<<dim3(32, 32, 4), dim3(32, 8), 0, stream>>>(
      Wq, Wk, Wv, Wo, WqT, WkT, WvT, WoT);

  GemmJob jq{Aq, WqT, bq, nullptr, Qp, 1};
  GemmJob jk{Ak, WkT, bk, nullptr, Kp, 1};
  GemmJob jv{Av, WvT, bv, nullptr, VTp, 2};
  gemm_multi<<<dim3(8, 32, 3), 256, 0, stream>>>(jq, jk, jv);

  attn_kernel<<<512, 512, 0, stream>>>(Qp, Kp, VTp, Ctx);

  GemmJob jo{Ctx, WoT, bo, out, nullptr, 0};
  gemm_multi<<<dim3(8, 32, 1), 256, 0, stream>>>(jo, jo, jo);
}

// Round 5
// 277.019 us; speedup vs baseline: 1.6829x; 1.0270x over previous
//
#include <hip/hip_runtime.h>

// MHA forward: B=2, S=2048, HID=1024, NH=16, HD=64.
// R5: GEMM grids get XCD-locality swizzle (xcd=blk&7 owns a 4-tile bm panel ×
//     all bn => 3MB/XCD L2 working set, was: consecutive bn-blocks sharing an
//     A-tile scattered across all 8 XCDs). Prep fused to one launch.
//     Attention unchanged from R4 (78us, L2-captured).

typedef unsigned short u16;
typedef unsigned int u32;
typedef __bf16 bf16x8 __attribute__((ext_vector_type(8)));
typedef float f32x4 __attribute__((ext_vector_type(4)));
typedef u16 u16x4 __attribute__((ext_vector_type(4)));

__device__ __forceinline__ u16 f2bf(float f) {
  union { float f; unsigned u; } x; x.f = f;
  unsigned r = (x.u + 0x7fffu + ((x.u >> 16) & 1u)) >> 16;  // RNE
  return (u16)r;
}

// async global->LDS, 16 B per lane. LDS dest is wave-uniform base + lane*16.
__device__ __forceinline__ void gll16(const void* g, void* l) {
  __builtin_amdgcn_global_load_lds(
      (const __attribute__((address_space(1))) u32*)g,
      (__attribute__((address_space(3))) u32*)l, 16, 0, 0);
}

// ---------------- prep (single launch) ----------------
// blocks 0..12287: cast query/key_/value fp32->bf16 (4096 blocks each)
// blocks 12288..16383: transpose+cast the 4 weights (1024 blocks each)
__global__ __launch_bounds__(256) void prep_kernel(
    const float* __restrict__ q32, const float* __restrict__ k32,
    const float* __restrict__ v32,
    u16* __restrict__ qb, u16* __restrict__ kb, u16* __restrict__ vb,
    const float* __restrict__ W0, const float* __restrict__ W1,
    const float* __restrict__ W2, const float* __restrict__ W3,
    u16* __restrict__ T0, u16* __restrict__ T1,
    u16* __restrict__ T2, u16* __restrict__ T3) {
  int blk = blockIdx.x, tid = threadIdx.x;
  if (blk < 12288) {
    int which = blk >> 12;
    const float* in = (which == 0) ? q32 : (which == 1) ? k32 : v32;
    u16* out = (which == 0) ? qb : (which == 1) ? kb : vb;
    int i = (blk & 4095) * 256 + tid;
    float4 v = ((const float4*)in)[i];
    u16x4 o;
    o.x = f2bf(v.x); o.y = f2bf(v.y); o.z = f2bf(v.z); o.w = f2bf(v.w);
    ((u16x4*)out)[i] = o;
  } else {
    int tb = blk - 12288;
    int z = tb >> 10, rest = tb & 1023;
    const float* W = (z == 0) ? W0 : (z == 1) ? W1 : (z == 2) ? W2 : W3;
    u16* WT = (z == 0) ? T0 : (z == 1) ? T1 : (z == 2) ? T2 : T3;
    __shared__ float t[32][33];
    int bx = (rest & 31) * 32, by = (rest >> 5) * 32;
    int tx = tid & 31, ty = tid >> 5;  // 32x8
#pragma unroll
    for (int i = ty; i < 32; i += 8) t[i][tx] = W[(by + i) * 1024 + bx + tx];
    __syncthreads();
#pragma unroll
    for (int i = ty; i < 32; i += 8) WT[(bx + i) * 1024 + by + tx] = f2bf(t[tx][i]);
  }
}

// ---------------- GEMM ----------------
// C = A(bf16,[M=4096,K=1024]) * B + bias, BT = B^T (bf16,[N=1024,K]).
// Flat grid njobs*256; z = blk>>8; within a job: xcd = blk&7 owns bm tiles
// xcd*4..xcd*4+3 (1MB A panel) x all 8 bn (2MB B) -> 3MB/XCD L2 set.
// LDS tiles 128x64, XOR-swizzled (slot (r,j') holds global chunk (r, j'^(r&7))).
struct GemmJob {
  const u16* A; const u16* BT; const float* bias;
  float* Cf; u16* Cb; int mode;
};

__global__ __launch_bounds__(256) void gemm_multi(GemmJob j0, GemmJob j1, GemmJob j2) {
  int blk = blockIdx.x;
  int z = blk >> 8, r0 = blk & 255;
  GemmJob j = (z == 0) ? j0 : (z == 1) ? j1 : j2;
  const int K = 1024, N = 1024;
  __shared__ __align__(16) u16 As[128 * 64];
  __shared__ __align__(16) u16 Bs[128 * 64];
  int tid = threadIdx.x;
  int xcd = r0 & 7, i5 = r0 >> 3;
  int bm = (xcd * 4 + (i5 & 3)) * 128;
  int bn = (i5 >> 2) * 128;
  int w = tid >> 6, lane = tid & 63, quad = lane >> 4, l16 = lane & 15;
  int wr = (w >> 1) * 64, wc = (w & 1) * 64;
  int l8 = l16 & 7;
  f32x4 acc[4][4] = {};

  for (int k0 = 0; k0 < K; k0 += 64) {
    __syncthreads();
#pragma unroll
    for (int i = 0; i < 4; ++i) {
      int c = tid + i * 256;                 // LDS chunk slot 0..1023
      int r = c >> 3, jp = c & 7;
      int jg = jp ^ (r & 7);                 // global chunk (XOR swizzle)
      gll16(&j.A[(size_t)(bm + r) * K + k0 + jg * 8], &As[c * 8]);
      gll16(&j.BT[(size_t)(bn + r) * K + k0 + jg * 8], &Bs[c * 8]);
    }
    __syncthreads();
#pragma unroll
    for (int ks = 0; ks < 2; ++ks) {
      bf16x8 af[4], bfr[4];
#pragma unroll
      for (int mt = 0; mt < 4; ++mt) {
        int row = wr + mt * 16 + l16;
        af[mt] = *(const bf16x8*)&As[row * 64 + (((ks * 4 + quad) ^ l8)) * 8];
      }
#pragma unroll
      for (int nt = 0; nt < 4; ++nt) {
        int row = wc + nt * 16 + l16;
        bfr[nt] = *(const bf16x8*)&Bs[row * 64 + (((ks * 4 + quad) ^ l8)) * 8];
      }
#pragma unroll
      for (int mt = 0; mt < 4; ++mt)
#pragma unroll
        for (int nt = 0; nt < 4; ++nt)
          acc[mt][nt] = __builtin_amdgcn_mfma_f32_16x16x32_bf16(af[mt], bfr[nt], acc[mt][nt], 0, 0, 0);
    }
  }

#pragma unroll
  for (int mt = 0; mt < 4; ++mt)
#pragma unroll
    for (int nt = 0; nt < 4; ++nt)
#pragma unroll
      for (int r = 0; r < 4; ++r) {
        int row = bm + wr + mt * 16 + quad * 4 + r;
        int col = bn + wc + nt * 16 + l16;
        float v = acc[mt][nt][r] + j.bias[col];
        if (j.mode == 0) {
          j.Cf[(size_t)row * N + col] = v;
        } else {
          int b = row >> 11, s = row & 2047, h = col >> 6, d = col & 63;
          u16 bv = f2bf(v);
          if (j.mode == 1)
            j.Cb[(((size_t)(b * 16 + h) * 2048 + s) << 6) + d] = bv;
          else
            j.Cb[((size_t)(b * 16 + h) * 64 + d) * 2048 + s] = bv;
        }
      }
}

// ---------------- flash attention (unchanged from R4) ----------------
__global__ __launch_bounds__(512) void attn_kernel(
    const u16* __restrict__ Q,   // [B*NH, S, 64]
    const u16* __restrict__ Kk,  // [B*NH, S, 64]
    const u16* __restrict__ VT,  // [B*NH, 64, S]
    u16* __restrict__ ctx)       // [B*S, 1024]
{
  __shared__ __align__(16) u16 Ks[128 * 64];
  __shared__ __align__(16) u16 Vs[64 * 128];
  __shared__ __align__(16) u16 PT[8 * 16 * 128];

  int blk = blockIdx.x;
  int qt = (blk >> 3) & 15;
  int bh = (blk & 7) * 4 + (blk >> 7);
  int b = bh >> 4, h = bh & 15;
  const u16* Qb = Q + ((size_t)bh * 2048 + qt * 128) * 64;
  const u16* Kb = Kk + (size_t)bh * 2048 * 64;
  const u16* Vb = VT + (size_t)bh * 64 * 2048;
  int tid = threadIdx.x, w = tid >> 6, lane = tid & 63, quad = lane >> 4, l16 = lane & 15;
  int rowbase = w * 16;
  u16* PTw = &PT[w * 16 * 128];

  bf16x8 qf[2];
#pragma unroll
  for (int ks = 0; ks < 2; ++ks)
    qf[ks] = *(const bf16x8*)&Qb[(rowbase + l16) * 64 + ks * 32 + quad * 8];

  f32x4 Oacc[4] = {};
  float lacc = 0.f;
  const float sc = 0.125f * 1.44269504f;

  for (int kv = 0; kv < 16; ++kv) {
    int kbase = kv * 128;
    __syncthreads();
#pragma unroll
    for (int i = 0; i < 2; ++i) {
      int c = tid + i * 512;
      int r = c >> 3, jp = c & 7, jg = jp ^ (r & 7);
      gll16(&Kb[(size_t)(kbase + r) * 64 + jg * 8], &Ks[c * 8]);
    }
#pragma unroll
    for (int i = 0; i < 2; ++i) {
      int c = tid + i * 512;
      int d = c >> 4, jp = c & 15, jg = jp ^ (d & 15);
      gll16(&Vb[(size_t)d * 2048 + kbase + jg * 8], &Vs[c * 8]);
    }
    __syncthreads();

    f32x4 Sacc[8] = {};
#pragma unroll
    for (int nt = 0; nt < 8; ++nt) {
      int r = nt * 16 + l16;
#pragma unroll
      for (int ks = 0; ks < 2; ++ks) {
        bf16x8 kfr = *(const bf16x8*)&Ks[r * 64 + ((ks * 4 + quad) ^ (l16 & 7)) * 8];
        Sacc[nt] = __builtin_amdgcn_mfma_f32_16x16x32_bf16(kfr, qf[ks], Sacc[nt], 0, 0, 0);
      }
    }

#pragma unroll
    for (int nt = 0; nt < 8; ++nt) {
      u16x4 pk;
#pragma unroll
      for (int r = 0; r < 4; ++r) {
        float p = exp2f(fmaf(Sacc[nt][r], sc, -24.0f));
        lacc += p;
        pk[r] = f2bf(p);
      }
      int jj = nt * 2 + (quad >> 1);
      *(u16x4*)&PTw[l16 * 128 + ((jj ^ l16) * 8) + (quad & 1) * 4] = pk;
    }

#pragma unroll
    for (int ks2 = 0; ks2 < 4; ++ks2) {
      bf16x8 pfB = *(const bf16x8*)&PTw[l16 * 128 + (((ks2 * 4 + quad) ^ l16)) * 8];
#pragma unroll
      for (int dt = 0; dt < 4; ++dt) {
        int d = dt * 16 + l16;
        bf16x8 vf = *(const bf16x8*)&Vs[d * 128 + (((ks2 * 4 + quad) ^ l16)) * 8];
        Oacc[dt] = __builtin_amdgcn_mfma_f32_16x16x32_bf16(vf, pfB, Oacc[dt], 0, 0, 0);
      }
    }
  }

  float l = lacc;
  l += __shfl_xor(l, 16, 64);
  l += __shfl_xor(l, 32, 64);
  float linv = 1.0f / l;

  int s = qt * 128 + rowbase + l16;
#pragma unroll
  for (int dt = 0; dt < 4; ++dt) {
    u16x4 o;
#pragma unroll
    for (int r = 0; r < 4; ++r) o[r] = f2bf(Oacc[dt][r] * linv);
    *(u16x4*)&ctx[(size_t)(b * 2048 + s) * 1024 + h * 64 + dt * 16 + quad * 4] = o;
  }
}

// ---------------- launch ----------------

extern "C" void kernel_launch(void* const* d_in, const int* in_sizes, int n_in,
                              void* d_out, int out_size, void* d_ws, size_t ws_size,
                              hipStream_t stream) {
  const float* query = (const float*)d_in[0];
  const float* key_  = (const float*)d_in[1];
  const float* value = (const float*)d_in[2];
  const float* Wq = (const float*)d_in[3];
  const float* bq = (const float*)d_in[4];
  const float* Wk = (const float*)d_in[5];
  const float* bk = (const float*)d_in[6];
  const float* Wv = (const float*)d_in[7];
  const float* bv = (const float*)d_in[8];
  const float* Wo = (const float*)d_in[9];
  const float* bo = (const float*)d_in[10];
  float* out = (float*)d_out;

  char* ws = (char*)d_ws;
  const size_t MB = 1024 * 1024;
  u16* Aq  = (u16*)(ws + 0 * MB);
  u16* Ak  = (u16*)(ws + 8 * MB);
  u16* Av  = (u16*)(ws + 16 * MB);
  u16* WqT = (u16*)(ws + 24 * MB);
  u16* WkT = (u16*)(ws + 26 * MB);
  u16* WvT = (u16*)(ws + 28 * MB);
  u16* WoT = (u16*)(ws + 30 * MB);
  u16* Qp  = (u16*)(ws + 32 * MB);
  u16* Kp  = (u16*)(ws + 40 * MB);
  u16* VTp = (u16*)(ws + 48 * MB);
  u16* Ctx = (u16*)(ws + 56 * MB);

  prep_kernel<<<16384, 256, 0, stream>>>(query, key_, value, Aq, Ak, Av,
                                         Wq, Wk, Wv, Wo, WqT, WkT, WvT, WoT);

  GemmJob jq{Aq, WqT, bq, nullptr, Qp, 1};
  GemmJob jk{Ak, WkT, bk, nullptr, Kp, 1};
  GemmJob jv{Av, WvT, bv, nullptr, VTp, 2};
  gemm_multi<<<768, 256, 0, stream>>>(jq, jk, jv);

  attn_kernel<<<512, 512, 0, stream>>>(Qp, Kp, VTp, Ctx);

  GemmJob jo{Ctx, WoT, bo, out, nullptr, 0};
  gemm_multi<<<256, 256, 0, stream>>>(jo, jo, jo);
}

// Round 6
// 273.714 us; speedup vs baseline: 1.7033x; 1.0121x over previous
//
#include <hip/hip_runtime.h>

// MHA forward: B=2, S=2048, HID=1024, NH=16, HD=64.
// R6: (1) softmax scale folded into Q-projection epilogue; attn does p=exp2f(S)
//     (common 2^-24 factor cancels in O/l). bf16 rounding via compiler casts
//     (hw packed cvt on gfx950) instead of 3-op sw RNE.
//     (2) QKV GEMM reads fp32 A directly (fp32 LDS tile + cvt at frag load);
//     input-cast prep pass deleted (saves 72MB traffic + one launch).
//     (3) prep = weight transposes only. Attention structure from R4/R5.

typedef unsigned short u16;
typedef unsigned int u32;
typedef __bf16 bf16x8 __attribute__((ext_vector_type(8)));
typedef float f32x4 __attribute__((ext_vector_type(4)));
typedef u16 u16x4 __attribute__((ext_vector_type(4)));

__device__ __forceinline__ u16 f2bf(float f) {
  __bf16 h = (__bf16)f;            // fptrunc RNE; hw cvt on gfx950
  return *(u16*)&h;
}

// async global->LDS, 16 B per lane. LDS dest is wave-uniform base + lane*16.
__device__ __forceinline__ void gll16(const void* g, void* l) {
  __builtin_amdgcn_global_load_lds(
      (const __attribute__((address_space(1))) u32*)g,
      (__attribute__((address_space(3))) u32*)l, 16, 0, 0);
}

// ---------------- prep: 4 weight transposes ----------------
// WT[n][k] = bf16(W[k][n]); grid (32,32,4), block (32,8)
__global__ void transpose4_kernel(
    const float* __restrict__ W0, const float* __restrict__ W1,
    const float* __restrict__ W2, const float* __restrict__ W3,
    u16* __restrict__ T0, u16* __restrict__ T1,
    u16* __restrict__ T2, u16* __restrict__ T3) {
  const float* W = (blockIdx.z == 0) ? W0 : (blockIdx.z == 1) ? W1
                  : (blockIdx.z == 2) ? W2 : W3;
  u16* WT = (blockIdx.z == 0) ? T0 : (blockIdx.z == 1) ? T1
           : (blockIdx.z == 2) ? T2 : T3;
  __shared__ float t[32][33];
  int bx = blockIdx.x * 32, by = blockIdx.y * 32;
  int tx = threadIdx.x, ty = threadIdx.y;
#pragma unroll
  for (int i = ty; i < 32; i += 8) t[i][tx] = W[(by + i) * 1024 + bx + tx];
  __syncthreads();
#pragma unroll
  for (int i = ty; i < 32; i += 8) WT[(bx + i) * 1024 + by + tx] = f2bf(t[tx][i]);
}

// ---------------- GEMM ----------------
// C = A([M=4096,K=1024], fp32 or bf16 per template) * B + bias; BT=B^T bf16.
// Flat grid; z=blk>>8 selects job; xcd=blk&7 owns 4 bm tiles x all bn (L2 local).
// A-tile LDS: fp32 path 32KB swizzle j^(r&15) (16B chunks, 16/row);
//             bf16 path 16KB swizzle j^(r&7) (8/row). B-tile bf16 16KB.
// Epilogue: v = (acc + bias[col]) * oscale  (oscale folds softmax scale into Q).
struct GemmJob {
  const void* A; const u16* BT; const float* bias;
  float* Cf; u16* Cb; int mode; float oscale;
};

template <bool F32A>
__global__ __launch_bounds__(256) void gemm_multi(GemmJob j0, GemmJob j1, GemmJob j2) {
  int blk = blockIdx.x;
  int z = blk >> 8, r0 = blk & 255;
  GemmJob j = (z == 0) ? j0 : (z == 1) ? j1 : j2;
  const int K = 1024, N = 1024;
  __shared__ __align__(16) float Asf[F32A ? 128 * 64 : 64];   // 32KB fp32 path
  __shared__ __align__(16) u16 Asb[F32A ? 16 : 128 * 64];     // 16KB bf16 path
  __shared__ __align__(16) u16 Bs[128 * 64];
  int tid = threadIdx.x;
  int xcd = r0 & 7, i5 = r0 >> 3;
  int bm = (xcd * 4 + (i5 & 3)) * 128;
  int bn = (i5 >> 2) * 128;
  int w = tid >> 6, lane = tid & 63, quad = lane >> 4, l16 = lane & 15;
  int wr = (w >> 1) * 64, wc = (w & 1) * 64;
  int l8 = l16 & 7;
  f32x4 acc[4][4] = {};

  for (int k0 = 0; k0 < K; k0 += 64) {
    __syncthreads();
    if (F32A) {
      const float* Af = (const float*)j.A;
#pragma unroll
      for (int i = 0; i < 8; ++i) {
        int c = tid + i * 256;                // 2048 chunks of 4 floats
        int r = c >> 4, jp = c & 15, jg = jp ^ (r & 15);
        gll16(&Af[(size_t)(bm + r) * K + k0 + jg * 4], &Asf[c * 4]);
      }
    } else {
      const u16* Ab = (const u16*)j.A;
#pragma unroll
      for (int i = 0; i < 4; ++i) {
        int c = tid + i * 256;                // 1024 chunks of 8 bf16
        int r = c >> 3, jp = c & 7, jg = jp ^ (r & 7);
        gll16(&Ab[(size_t)(bm + r) * K + k0 + jg * 8], &Asb[c * 8]);
      }
    }
#pragma unroll
    for (int i = 0; i < 4; ++i) {
      int c = tid + i * 256;
      int r = c >> 3, jp = c & 7, jg = jp ^ (r & 7);
      gll16(&j.BT[(size_t)(bn + r) * K + k0 + jg * 8], &Bs[c * 8]);
    }
    __syncthreads();
#pragma unroll
    for (int ks = 0; ks < 2; ++ks) {
      bf16x8 af[4], bfr[4];
#pragma unroll
      for (int mt = 0; mt < 4; ++mt) {
        int row = wr + mt * 16 + l16;
        if (F32A) {
          int c0 = ks * 8 + quad * 2;
          f32x4 a0 = *(const f32x4*)&Asf[(row * 16 + (c0 ^ (row & 15))) * 4];
          f32x4 a1 = *(const f32x4*)&Asf[(row * 16 + ((c0 + 1) ^ (row & 15))) * 4];
#pragma unroll
          for (int jj = 0; jj < 4; ++jj) {
            af[mt][jj] = (__bf16)a0[jj];
            af[mt][jj + 4] = (__bf16)a1[jj];
          }
        } else {
          af[mt] = *(const bf16x8*)&Asb[row * 64 + (((ks * 4 + quad) ^ l8)) * 8];
        }
      }
#pragma unroll
      for (int nt = 0; nt < 4; ++nt) {
        int row = wc + nt * 16 + l16;
        bfr[nt] = *(const bf16x8*)&Bs[row * 64 + (((ks * 4 + quad) ^ l8)) * 8];
      }
#pragma unroll
      for (int mt = 0; mt < 4; ++mt)
#pragma unroll
        for (int nt = 0; nt < 4; ++nt)
          acc[mt][nt] = __builtin_amdgcn_mfma_f32_16x16x32_bf16(af[mt], bfr[nt], acc[mt][nt], 0, 0, 0);
    }
  }

#pragma unroll
  for (int mt = 0; mt < 4; ++mt)
#pragma unroll
    for (int nt = 0; nt < 4; ++nt)
#pragma unroll
      for (int r = 0; r < 4; ++r) {
        int row = bm + wr + mt * 16 + quad * 4 + r;
        int col = bn + wc + nt * 16 + l16;
        float v = (acc[mt][nt][r] + j.bias[col]) * j.oscale;
        if (j.mode == 0) {
          j.Cf[(size_t)row * N + col] = v;
        } else {
          int b = row >> 11, s = row & 2047, h = col >> 6, d = col & 63;
          u16 bv = f2bf(v);
          if (j.mode == 1)
            j.Cb[(((size_t)(b * 16 + h) * 2048 + s) << 6) + d] = bv;
          else
            j.Cb[((size_t)(b * 16 + h) * 64 + d) * 2048 + s] = bv;
        }
      }
}

// ---------------- flash attention ----------------
// Flat grid 512, block 512 (8 waves x 16 q-rows). Q pre-scaled by
// 0.125*log2(e) at projection => p = exp2f(S) directly (common factor cancels
// in O/l). K/V staged to LDS via gll16, XOR-swizzled. S^T formulation,
// P^T wave-private in LDS, barrier count 2/kv-iter (staging only).
__global__ __launch_bounds__(512) void attn_kernel(
    const u16* __restrict__ Q,   // [B*NH, S, 64] (pre-scaled)
    const u16* __restrict__ Kk,  // [B*NH, S, 64]
    const u16* __restrict__ VT,  // [B*NH, 64, S]
    u16* __restrict__ ctx)       // [B*S, 1024]
{
  __shared__ __align__(16) u16 Ks[128 * 64];
  __shared__ __align__(16) u16 Vs[64 * 128];
  __shared__ __align__(16) u16 PT[8 * 16 * 128];

  int blk = blockIdx.x;
  int qt = (blk >> 3) & 15;
  int bh = (blk & 7) * 4 + (blk >> 7);
  int b = bh >> 4, h = bh & 15;
  const u16* Qb = Q + ((size_t)bh * 2048 + qt * 128) * 64;
  const u16* Kb = Kk + (size_t)bh * 2048 * 64;
  const u16* Vb = VT + (size_t)bh * 64 * 2048;
  int tid = threadIdx.x, w = tid >> 6, lane = tid & 63, quad = lane >> 4, l16 = lane & 15;
  int rowbase = w * 16;
  u16* PTw = &PT[w * 16 * 128];

  bf16x8 qf[2];
#pragma unroll
  for (int ks = 0; ks < 2; ++ks)
    qf[ks] = *(const bf16x8*)&Qb[(rowbase + l16) * 64 + ks * 32 + quad * 8];

  f32x4 Oacc[4] = {};
  float lacc = 0.f;

  for (int kv = 0; kv < 16; ++kv) {
    int kbase = kv * 128;
    __syncthreads();
#pragma unroll
    for (int i = 0; i < 2; ++i) {
      int c = tid + i * 512;
      int r = c >> 3, jp = c & 7, jg = jp ^ (r & 7);
      gll16(&Kb[(size_t)(kbase + r) * 64 + jg * 8], &Ks[c * 8]);
    }
#pragma unroll
    for (int i = 0; i < 2; ++i) {
      int c = tid + i * 512;
      int d = c >> 4, jp = c & 15, jg = jp ^ (d & 15);
      gll16(&Vb[(size_t)d * 2048 + kbase + jg * 8], &Vs[c * 8]);
    }
    __syncthreads();

    f32x4 Sacc[8] = {};
#pragma unroll
    for (int nt = 0; nt < 8; ++nt) {
      int r = nt * 16 + l16;
#pragma unroll
      for (int ks = 0; ks < 2; ++ks) {
        bf16x8 kfr = *(const bf16x8*)&Ks[r * 64 + ((ks * 4 + quad) ^ (l16 & 7)) * 8];
        Sacc[nt] = __builtin_amdgcn_mfma_f32_16x16x32_bf16(kfr, qf[ks], Sacc[nt], 0, 0, 0);
      }
    }

#pragma unroll
    for (int nt = 0; nt < 8; ++nt) {
      u16x4 pk;
#pragma unroll
      for (int r = 0; r < 4; ++r) {
        float p = exp2f(Sacc[nt][r]);   // scale pre-folded into Q
        lacc += p;
        pk[r] = f2bf(p);
      }
      int jj = nt * 2 + (quad >> 1);
      *(u16x4*)&PTw[l16 * 128 + ((jj ^ l16) * 8) + (quad & 1) * 4] = pk;
    }

#pragma unroll
    for (int ks2 = 0; ks2 < 4; ++ks2) {
      bf16x8 pfB = *(const bf16x8*)&PTw[l16 * 128 + (((ks2 * 4 + quad) ^ l16)) * 8];
#pragma unroll
      for (int dt = 0; dt < 4; ++dt) {
        int d = dt * 16 + l16;
        bf16x8 vf = *(const bf16x8*)&Vs[d * 128 + (((ks2 * 4 + quad) ^ l16)) * 8];
        Oacc[dt] = __builtin_amdgcn_mfma_f32_16x16x32_bf16(vf, pfB, Oacc[dt], 0, 0, 0);
      }
    }
  }

  float l = lacc;
  l += __shfl_xor(l, 16, 64);
  l += __shfl_xor(l, 32, 64);
  float linv = 1.0f / l;

  int s = qt * 128 + rowbase + l16;
#pragma unroll
  for (int dt = 0; dt < 4; ++dt) {
    u16x4 o;
#pragma unroll
    for (int r = 0; r < 4; ++r) o[r] = f2bf(Oacc[dt][r] * linv);
    *(u16x4*)&ctx[(size_t)(b * 2048 + s) * 1024 + h * 64 + dt * 16 + quad * 4] = o;
  }
}

// ---------------- launch ----------------

extern "C" void kernel_launch(void* const* d_in, const int* in_sizes, int n_in,
                              void* d_out, int out_size, void* d_ws, size_t ws_size,
                              hipStream_t stream) {
  const float* query = (const float*)d_in[0];
  const float* key_  = (const float*)d_in[1];
  const float* value = (const float*)d_in[2];
  const float* Wq = (const float*)d_in[3];
  const float* bq = (const float*)d_in[4];
  const float* Wk = (const float*)d_in[5];
  const float* bk = (const float*)d_in[6];
  const float* Wv = (const float*)d_in[7];
  const float* bv = (const float*)d_in[8];
  const float* Wo = (const float*)d_in[9];
  const float* bo = (const float*)d_in[10];
  float* out = (float*)d_out;

  char* ws = (char*)d_ws;
  const size_t MB = 1024 * 1024;
  u16* WqT = (u16*)(ws + 0 * MB);
  u16* WkT = (u16*)(ws + 2 * MB);
  u16* WvT = (u16*)(ws + 4 * MB);
  u16* WoT = (u16*)(ws + 6 * MB);
  u16* Qp  = (u16*)(ws + 8 * MB);    // [B*NH, S, 64] pre-scaled
  u16* Kp  = (u16*)(ws + 16 * MB);
  u16* VTp = (u16*)(ws + 24 * MB);   // [B*NH, 64, S]
  u16* Ctx = (u16*)(ws + 32 * MB);   // [4096, 1024]

  transpose4_kernel<<<dim3(32, 32, 4), dim3(32, 8), 0, stream>>>(
      Wq, Wk, Wv, Wo, WqT, WkT, WvT, WoT);

  const float sc = 0.125f * 1.44269504f;  // 1/sqrt(64) * log2(e)
  GemmJob jq{query, WqT, bq, nullptr, Qp, 1, sc};
  GemmJob jk{key_, WkT, bk, nullptr, Kp, 1, 1.0f};
  GemmJob jv{value, WvT, bv, nullptr, VTp, 2, 1.0f};
  gemm_multi<true><<<768, 256, 0, stream>>>(jq, jk, jv);

  attn_kernel<<<512, 512, 0, stream>>>(Qp, Kp, VTp, Ctx);

  GemmJob jo{Ctx, WoT, bo, out, nullptr, 0, 1.0f};
  gemm_multi<false><<<256, 256, 0, stream>>>(jo, jo, jo);
}